// Round 4
// baseline (299.885 us; speedup 1.0000x reference)
//
#include <hip/hip_runtime.h>

// QuantumRNNCell, v4: shuffle-free sim + copy-style streaming epilogue.
//   Kernel 1 (sim): ONE THREAD per batch element holds all 64 complex
//     amplitudes in registers; gates are pure VALU, CNOT ring is a
//     compile-time register permutation. Writes q6 (B,6) to d_ws.
//   Kernel 2 (epilogue): out = hx + q6 @ fc_w^T + fc_b, structured exactly
//     like the 6.3 TB/s float4 copy ubench: ONE float4 per thread, one
//     block per batch row (grid=B=32768). TLP (512 waves/CU queued) does
//     the latency hiding -- no per-wave serial chain for the scheduler to
//     collapse (v3's explicit 8-deep batching was defeated by the
//     register-pressure scheduler: VGPR_Count=36 proved the loads sank).
//
// Wire w <-> bit (5-w) of the state index (wire 0 = MSB, pennylane order).

#define NQ 6
#define DIM 64

// ---- composed CNOT ring permutation: A'[s] = A[PS.v[s]] ----
struct Perm { int v[DIM]; };
constexpr Perm make_perm() {
    Perm p{};
    for (int s = 0; s < DIM; ++s) {
        int src = s;
        for (int q = 5; q >= 0; --q) {          // apply g5 first, g0 last
            int cb = 5 - q;                      // control bit of CNOT(q, q+1)
            int tb = 5 - ((q + 1) % 6);          // target bit
            src ^= ((src >> cb) & 1) << tb;
        }
        p.v[s] = src;
    }
    return p;
}
constexpr Perm PS = make_perm();

// RX: [[c,-is],[-is,c]]
template<int BB>
__device__ __forceinline__ void rx_gate(float* sr, float* si, float c, float sn) {
    constexpr int m = 1 << BB;
    #pragma unroll
    for (int p = 0; p < 32; ++p) {
        const int s0 = ((p & ~(m - 1)) << 1) | (p & (m - 1));
        const int s1 = s0 | m;
        float a0r = sr[s0], a0i = si[s0], a1r = sr[s1], a1i = si[s1];
        sr[s0] = c * a0r + sn * a1i;
        si[s0] = c * a0i - sn * a1r;
        sr[s1] = c * a1r + sn * a0i;
        si[s1] = c * a1i - sn * a0r;
    }
}

// RY: [[c,-s],[s,c]]
template<int BB>
__device__ __forceinline__ void ry_gate(float* sr, float* si, float c, float sn) {
    constexpr int m = 1 << BB;
    #pragma unroll
    for (int p = 0; p < 32; ++p) {
        const int s0 = ((p & ~(m - 1)) << 1) | (p & (m - 1));
        const int s1 = s0 | m;
        float a0r = sr[s0], a0i = si[s0], a1r = sr[s1], a1i = si[s1];
        sr[s0] = c * a0r - sn * a1r;
        si[s0] = c * a0i - sn * a1i;
        sr[s1] = sn * a0r + c * a1r;
        si[s1] = sn * a0i + c * a1i;
    }
}

// RZ: diag(e^{-i t/2}, e^{+i t/2})
template<int BB>
__device__ __forceinline__ void rz_gate(float* sr, float* si, float c, float sn) {
    constexpr int m = 1 << BB;
    #pragma unroll
    for (int s = 0; s < DIM; ++s) {
        float r = sr[s], i2 = si[s];
        if (s & m) { sr[s] = c * r - sn * i2;  si[s] = c * i2 + sn * r; }
        else       { sr[s] = c * r + sn * i2;  si[s] = c * i2 - sn * r; }
    }
}

__device__ __forceinline__ void cnot_ring(float* sr, float* si) {
    float tr[DIM], ti[DIM];
    #pragma unroll
    for (int s = 0; s < DIM; ++s) { tr[s] = sr[PS.v[s]]; ti[s] = si[PS.v[s]]; }
    #pragma unroll
    for (int s = 0; s < DIM; ++s) { sr[s] = tr[s]; si[s] = ti[s]; }
}

__global__ __launch_bounds__(64, 1) void qrnn_sim_kernel(
    const float* __restrict__ x,     // (B, 6)
    const float* __restrict__ qw,    // (3, 6)
    float* __restrict__ q6,          // (B, 6) out
    int B)
{
    const int b = blockIdx.x * 64 + threadIdx.x;
    if (b >= B) return;

    float cx[6], sx[6];
    #pragma unroll
    for (int i = 0; i < 6; ++i)
        __sincosf(x[(size_t)b * 6 + i] * 0.5f, &sx[i], &cx[i]);

    float sr[DIM], si[DIM];
    #pragma unroll
    for (int s = 0; s < DIM; ++s) { sr[s] = (s == 0) ? 1.0f : 0.0f; si[s] = 0.0f; }

    // encoding: RX(x[i]), RY(x[i+1]), RZ(x[i+2]) on wire i (bit 5-i)
    #define ENC_WIRE(i) \
        rx_gate<5-(i)>(sr, si, cx[(i)],       sx[(i)]); \
        ry_gate<5-(i)>(sr, si, cx[((i)+1)%6], sx[((i)+1)%6]); \
        rz_gate<5-(i)>(sr, si, cx[((i)+2)%6], sx[((i)+2)%6]);
    ENC_WIRE(0) ENC_WIRE(1) ENC_WIRE(2) ENC_WIRE(3) ENC_WIRE(4) ENC_WIRE(5)
    #undef ENC_WIRE

    // variational layers: RY(qw[l][q]) on wire q, then CNOT ring
    #define VAR_GATE(l, q) { \
        float c, s2; __sincosf(qw[(l)*6+(q)] * 0.5f, &s2, &c); \
        ry_gate<5-(q)>(sr, si, c, s2); }
    #define VAR_LAYER(l) \
        VAR_GATE(l,0) VAR_GATE(l,1) VAR_GATE(l,2) \
        VAR_GATE(l,3) VAR_GATE(l,4) VAR_GATE(l,5) \
        cnot_ring(sr, si);
    VAR_LAYER(0) VAR_LAYER(1) VAR_LAYER(2)
    #undef VAR_LAYER
    #undef VAR_GATE

    // PauliZ expvals: q[j] = sum_s (1 - 2*bit_{5-j}(s)) * |amp_s|^2
    float q[6] = {0.f, 0.f, 0.f, 0.f, 0.f, 0.f};
    #pragma unroll
    for (int s = 0; s < DIM; ++s) {
        float p = sr[s] * sr[s] + si[s] * si[s];
        #pragma unroll
        for (int j = 0; j < 6; ++j)
            q[j] += (s & (1 << (5 - j))) ? -p : p;   // sign is compile-time
    }
    #pragma unroll
    for (int j = 0; j < 6; ++j) q6[(size_t)b * 6 + j] = q[j];
}

// ---- epilogue: out[b][h] = hx[b][h] + sum_j q6[b][j]*fc_w[h][j] + fc_b[h] ----
// Copy-ubench-isomorphic: one block per batch row b, one float4 per thread.
// q6 row is block-uniform (scalarizes); fc_w/fc_b are L1-resident (28 KB).
__global__ __launch_bounds__(256) void qrnn_epi_kernel(
    const float* __restrict__ hx,    // (B, H)
    const float* __restrict__ q6,    // (B, 6)
    const float* __restrict__ fc_w,  // (H, 6)
    const float* __restrict__ fc_b,  // (H,)
    float* __restrict__ out,         // (B, H)
    int H)
{
    const int b  = blockIdx.x;
    const int h4 = threadIdx.x;              // float4 column, < H/4 = 256

    // issue the HBM load first so it's in flight during the cache-hit loads
    float4 hv = ((const float4*)(hx + (size_t)b * H))[h4];

    // block-uniform q6 row -> scalar loads
    const float* qb = q6 + (size_t)b * 6;
    float q0 = qb[0], q1 = qb[1], q2 = qb[2];
    float q3 = qb[3], q4 = qb[4], q5 = qb[5];

    // this thread's 4 fc_w rows (24 floats = 6 aligned float4) + bias (L1-hit)
    const float4* w4 = (const float4*)fc_w;
    const int wb = h4 * 6;
    float4 a0 = w4[wb + 0], a1 = w4[wb + 1], a2 = w4[wb + 2];
    float4 a3 = w4[wb + 3], a4 = w4[wb + 4], a5 = w4[wb + 5];
    float4 bv = ((const float4*)fc_b)[h4];

    float4 res;
    res.x = hv.x + bv.x + q0*a0.x + q1*a0.y + q2*a0.z + q3*a0.w + q4*a1.x + q5*a1.y;
    res.y = hv.y + bv.y + q0*a1.z + q1*a1.w + q2*a2.x + q3*a2.y + q4*a2.z + q5*a2.w;
    res.z = hv.z + bv.z + q0*a3.x + q1*a3.y + q2*a3.z + q3*a3.w + q4*a4.x + q5*a4.y;
    res.w = hv.w + bv.w + q0*a4.z + q1*a4.w + q2*a5.x + q3*a5.y + q4*a5.z + q5*a5.w;
    ((float4*)(out + (size_t)b * H))[h4] = res;
}

extern "C" void kernel_launch(void* const* d_in, const int* in_sizes, int n_in,
                              void* d_out, int out_size, void* d_ws, size_t ws_size,
                              hipStream_t stream) {
    const float* x    = (const float*)d_in[0];   // (B, 6)
    const float* hx   = (const float*)d_in[1];   // (B, H)
    const float* qw   = (const float*)d_in[2];   // (3, 6)
    const float* fc_w = (const float*)d_in[3];   // (H, 6)
    const float* fc_b = (const float*)d_in[4];   // (H,)
    float* out = (float*)d_out;

    const int B = in_sizes[0] / NQ;              // 32768
    const int H = in_sizes[4];                   // 1024

    float* q6 = (float*)d_ws;                    // (B, 6) scratch, 768 KB

    qrnn_sim_kernel<<<(B + 63) / 64, 64, 0, stream>>>(x, qw, q6, B);
    // one block per batch row; one float4 per thread (H/4 = 256 threads)
    qrnn_epi_kernel<<<B, H / 4, 0, stream>>>(hx, q6, fc_w, fc_b, out, H);
}